// Round 6
// baseline (447.773 us; speedup 1.0000x reference)
//
#include <hip/hip_runtime.h>

// DelayBuffer: embeddings [B=4, S=4096, D=1024] f32.
// out[b, t, di*D + c] = emb[b, t - d, c] if t >= d else emb[b, t, c],  d = 1<<di.
//
// R6: OUTPUT-CONTIGUOUS gather. Each block owns 48 consecutive output 4-KB
// rows (8 (b,t)-groups x 6 delays) = one 192 KB sequential write stream —
// matching the long-stream pattern that lets the harness fill hit 6.4 TB/s.
// Reads: per group, 6 cached loads from rows t-d (clamped to t for t<d).
// Input is 67 MB with 6x reuse -> L2/L3 absorb the reuse; HBM reads ~= 67 MB.
//
// Per thread per group: 6 independent loads -> 6 stores into consecutive
// 4-KB rows. All accesses 16 B/lane, fully coalesced. Branch conditions
// uniform in t -> no divergence.

using f32x4 = __attribute__((ext_vector_type(4))) float;

constexpr unsigned B   = 4;
constexpr unsigned S   = 4096;           // power of two
constexpr unsigned ND  = 6;              // delays d = 1<<di
constexpr unsigned D4  = 1024 / 4;       // f32x4 per row = 256
constexpr unsigned NBT = B * S;          // 16384 (b,t) groups
constexpr unsigned GPB = 8;              // groups per block
constexpr unsigned NBLK = NBT / GPB;     // 2048 blocks

__global__ __launch_bounds__(256) void delay_gather(
    const f32x4* __restrict__ in, f32x4* __restrict__ out) {
    const unsigned tid = threadIdx.x;
    const unsigned bt0 = blockIdx.x * GPB;

    for (unsigned g = 0; g < GPB; ++g) {
        const unsigned bt = bt0 + g;
        const unsigned t  = bt & (S - 1);

        // 6 independent cached loads (sources hit L2/L3 after first touch).
        f32x4 v[ND];
        #pragma unroll
        for (unsigned di = 0; di < ND; ++di) {
            const unsigned d      = 1u << di;
            const unsigned src_bt = (t >= d) ? (bt - d) : bt;
            v[di] = in[(size_t)src_bt * D4 + tid];
        }

        // 6 stores into consecutive 4-KB output rows -> block writes one
        // sequential 192 KB stream over its 8 groups.
        const size_t ob = (size_t)bt * (ND * D4) + tid;
        #pragma unroll
        for (unsigned di = 0; di < ND; ++di)
            out[ob + (size_t)di * D4] = v[di];
    }
}

extern "C" void kernel_launch(void* const* d_in, const int* in_sizes, int n_in,
                              void* d_out, int out_size, void* d_ws, size_t ws_size,
                              hipStream_t stream) {
    const f32x4* in  = (const f32x4*)d_in[0];
    f32x4*       out = (f32x4*)d_out;

    delay_gather<<<NBLK, 256, 0, stream>>>(in, out);
}